// Round 1
// baseline (1003.480 us; speedup 1.0000x reference)
//
#include <hip/hip_runtime.h>
#include <math.h>

// B=4, T=2048, D=1024, H=16, HD=64
#define B_  4
#define T_  2048
#define D_  1024
#define H_  16
#define HD_ 64

typedef unsigned short ushort_t;
typedef unsigned int uint_t;
typedef __attribute__((ext_vector_type(8))) short bf16x8;
typedef __attribute__((ext_vector_type(4))) float f32x4;

// 0.125 * log2(e): folds 1/sqrt(HD) and exp->exp2.
#define SC_LOG2 0.1803368801111243f

__device__ inline ushort_t f2bf(float f) {           // RNE
  uint_t u = __float_as_uint(f);
  u += 0x7fffu + ((u >> 16) & 1u);
  return (ushort_t)(u >> 16);
}
__device__ inline ushort_t f2bf_fast(float f) {      // round-half-away
  return (ushort_t)((__float_as_uint(f) + 0x8000u) >> 16);
}
__device__ inline uint_t pack2bf(float a, float b) { // (a lo16, b hi16)
  uint_t ua = (__float_as_uint(a) + 0x8000u) >> 16;
  uint_t ub = (__float_as_uint(b) + 0x8000u) & 0xffff0000u;
  return ua | ub;
}

__device__ inline void gload_lds16(const ushort_t* g, ushort_t* l) {
  __builtin_amdgcn_global_load_lds(
      (const __attribute__((address_space(1))) unsigned int*)g,
      (__attribute__((address_space(3))) unsigned int*)l, 16, 0, 0);
}

// V pack: key -> group gp, slot j0 (pi grouping so P regs form a valid A-frag)
__device__ inline void v_pack_store(ushort_t* Vb, uint4 va, uint4 vc,
                                    int gp, int cc, int j0) {
  uint_t* dst = (uint_t*)&Vb[gp * 520 + cc * 64 + j0];
  dst[0]  = (va.x & 0xffffu) | (vc.x << 16);
  dst[4]  = (va.x >> 16)     | (vc.x & 0xffff0000u);
  dst[8]  = (va.y & 0xffffu) | (vc.y << 16);
  dst[12] = (va.y >> 16)     | (vc.y & 0xffff0000u);
  dst[16] = (va.z & 0xffffu) | (vc.z << 16);
  dst[20] = (va.z >> 16)     | (vc.z & 0xffff0000u);
  dst[24] = (va.w & 0xffffu) | (vc.w << 16);
  dst[28] = (va.w >> 16)     | (vc.w & 0xffff0000u);
}

// ---------------------------------------------------------------------------
__global__ __launch_bounds__(256) void cvt_bf16(const float* __restrict__ in,
                                                ushort_t* __restrict__ out, int n) {
  int i = (blockIdx.x * 256 + threadIdx.x) * 4;
  if (i + 3 < n) {
    float4 v = *(const float4*)(in + i);
    uint_t lo = (uint_t)f2bf(v.x) | ((uint_t)f2bf(v.y) << 16);
    uint_t hi = (uint_t)f2bf(v.z) | ((uint_t)f2bf(v.w) << 16);
    *(uint2*)(out + i) = make_uint2(lo, hi);
  }
}

// per-key bias in log2 domain: masked ? -1e30 : log2(clip(engagement,1e-6))
__global__ __launch_bounds__(256) void bias_prep(const float* __restrict__ eng,
                                                 const int* __restrict__ mask,
                                                 float* __restrict__ biasA, int n) {
  int i = blockIdx.x * 256 + threadIdx.x;
  if (i < n) biasA[i] = mask[i] ? -1e30f : __log2f(fmaxf(eng[i], 1e-6f));
}

// ---------------------------------------------------------------------------
// C[M,N] = A[M,K] @ B[N,K]^T + bias[N]. (unchanged)
// ---------------------------------------------------------------------------
template <int WRITE_BF16>
__global__ __launch_bounds__(256) void gemm_bf16(
    const ushort_t* __restrict__ A, const ushort_t* __restrict__ Bm,
    const float* __restrict__ bias, void* __restrict__ Cout,
    int M, int N, int K) {
  __shared__ __align__(16) ushort_t Ls[8192];
  ushort_t* As = Ls;
  ushort_t* Bs = Ls + 4096;
  const int tid = threadIdx.x;
  const int w = tid >> 6, lane = tid & 63;
  const int l15 = lane & 15, quad = lane >> 4;
  const int wm = w >> 1, wn = w & 1;
  const int m0 = blockIdx.y * 128, n0 = blockIdx.x * 128;

  f32x4 acc[4][4];
#pragma unroll
  for (int a = 0; a < 4; ++a)
#pragma unroll
    for (int b = 0; b < 4; ++b) acc[a][b] = (f32x4){0.f, 0.f, 0.f, 0.f};

  const int sr = lane >> 2;
  const int gc = (lane & 3) ^ ((sr >> 1) & 3);

  for (int k0 = 0; k0 < K; k0 += 32) {
    __syncthreads();
#pragma unroll
    for (int u = 0; u < 2; ++u) {
      int row = w * 32 + u * 16 + sr;
      gload_lds16(A + (size_t)(m0 + row) * K + k0 + gc * 8,
                  &As[(w * 32 + u * 16) * 32]);
      gload_lds16(Bm + (size_t)(n0 + row) * K + k0 + gc * 8,
                  &Bs[(w * 32 + u * 16) * 32]);
    }
    __syncthreads();
    bf16x8 af[4], bf[4];
#pragma unroll
    for (int mb = 0; mb < 4; ++mb) {
      int row = wm * 64 + mb * 16 + l15;
      int p = quad ^ ((l15 >> 1) & 3);
      af[mb] = *(const bf16x8*)(&As[row * 32 + p * 8]);
    }
#pragma unroll
    for (int nb = 0; nb < 4; ++nb) {
      int row = wn * 64 + nb * 16 + l15;
      int p = quad ^ ((l15 >> 1) & 3);
      bf[nb] = *(const bf16x8*)(&Bs[row * 32 + p * 8]);
    }
#pragma unroll
    for (int mb = 0; mb < 4; ++mb)
#pragma unroll
      for (int nb = 0; nb < 4; ++nb)
        acc[mb][nb] = __builtin_amdgcn_mfma_f32_16x16x32_bf16(
            af[mb], bf[nb], acc[mb][nb], 0, 0, 0);
  }

  float bb[4];
#pragma unroll
  for (int nb = 0; nb < 4; ++nb) bb[nb] = bias[n0 + wn * 64 + nb * 16 + l15];

  if (WRITE_BF16) {
    ushort_t* Cb = (ushort_t*)Cout;
#pragma unroll
    for (int mb = 0; mb < 4; ++mb) {
      __syncthreads();
#pragma unroll
      for (int nb = 0; nb < 4; ++nb)
#pragma unroll
        for (int i = 0; i < 4; ++i) {
          float v = acc[mb][nb][i] + bb[nb];
          Ls[(wm * 16 + quad * 4 + i) * 136 + wn * 64 + nb * 16 + l15] =
              f2bf_fast(v);
        }
      __syncthreads();
      int lr = tid >> 3, c = tid & 7;
      size_t gr = (size_t)(m0 + (lr >> 4) * 64 + mb * 16 + (lr & 15));
      uint4 v0 = *(const uint4*)&Ls[lr * 136 + c * 16];
      uint4 v1 = *(const uint4*)&Ls[lr * 136 + c * 16 + 8];
      *(uint4*)&Cb[gr * N + n0 + c * 16] = v0;
      *(uint4*)&Cb[gr * N + n0 + c * 16 + 8] = v1;
    }
  } else {
    float* Cf = (float*)Cout;
#pragma unroll
    for (int mb = 0; mb < 4; ++mb)
#pragma unroll
      for (int i = 0; i < 4; ++i) {
        size_t row = (size_t)(m0 + wm * 64 + mb * 16 + quad * 4 + i);
#pragma unroll
        for (int nb = 0; nb < 4; ++nb)
          Cf[row * N + n0 + wn * 64 + nb * 16 + l15] = acc[mb][nb][i] + bb[nb];
      }
  }
}

// ---------------------------------------------------------------------------
// MFMA flash attention, S^T formulation — now software-pipelined:
// double-buffered K/V/bias, ONE barrier per 64-key tile, next tile's
// global loads issued before current tile's compute (T3-minimal + T14).
// LDS (34048 B, 4 blocks/CU):
//   Kb0 @0 (8192) | Kb1 @8192 (8192) | Vb0 @16384 (8320) | Vb1 @24704 (8320)
//   bsh0 @33024 (256) | bsh1 @33280 (256) | lsum @33536 (512)
//   Ost  @0 (18432) — epilogue only, aliases Kb/Vb (safe after final barrier)
// ---------------------------------------------------------------------------
__global__ __launch_bounds__(256, 4) void attn_mfma(
    const ushort_t* __restrict__ qkv, const float* __restrict__ biasA,
    ushort_t* __restrict__ oat) {
  __shared__ __align__(16) char smem[34048];
  ushort_t* Kb0 = (ushort_t*)(smem);
  ushort_t* Kb1 = (ushort_t*)(smem + 8192);
  ushort_t* Vb0 = (ushort_t*)(smem + 16384);
  ushort_t* Vb1 = (ushort_t*)(smem + 24704);
  float* bsh0 = (float*)(smem + 33024);
  float* bsh1 = (float*)(smem + 33280);
  float (*lsum)[32] = (float (*)[32])(smem + 33536);

  const int b = blockIdx.z, h = blockIdx.y;
  const int q0 = blockIdx.x * 128;
  const int tid = threadIdx.x;
  const int w = tid >> 6, lane = tid & 63;
  const int l15 = lane & 15, quad = lane >> 4;
  const size_t rs = 3 * D_;

  // Q B-frags (n=l15=q, k=quad*8+j=d) for the wave's 2 q-blocks.
  bf16x8 qf[2][2];
#pragma unroll
  for (int qb = 0; qb < 2; ++qb) {
    const ushort_t* qp =
        qkv + (size_t)(b * T_ + q0 + w * 32 + qb * 16 + l15) * rs + h * HD_;
    qf[qb][0] = *(const bf16x8*)(qp + quad * 8);
    qf[qb][1] = *(const bf16x8*)(qp + 32 + quad * 8);
  }

  f32x4 Oa[2][4];
#pragma unroll
  for (int qb = 0; qb < 2; ++qb)
#pragma unroll
    for (int nb = 0; nb < 4; ++nb) Oa[qb][nb] = (f32x4){0.f, 0.f, 0.f, 0.f};
  float rsum[2] = {0.f, 0.f};

  const ushort_t* kbase = qkv + (size_t)(b * T_) * rs + D_ + h * HD_;
  const ushort_t* vbase = kbase + D_;
  const float* bptr = biasA + b * T_;

  const int kr = lane >> 3, kc = lane & 7;
  const int kgc = kc ^ kr;
  const int kp = tid & 31, cc = tid >> 5;
  const int gp = (kp >> 4) * 4 + ((kp >> 1) & 3);
  const int j0 = ((kp >> 3) & 1) * 4 + 2 * (kp & 1);

  // ---- prologue: stage tile 0 into buf0
  {
#pragma unroll
    for (int u = 0; u < 2; ++u)
      gload_lds16(kbase + (size_t)(w * 16 + u * 8 + kr) * rs + kgc * 8,
                  &Kb0[(w * 16 + u * 8) * 64]);
    const ushort_t* vp = vbase + (size_t)(2 * kp) * rs + cc * 8;
    uint4 va = *(const uint4*)vp;
    uint4 vc = *(const uint4*)(vp + rs);
    if (tid < 64) bsh0[tid] = bptr[tid];
    v_pack_store(Vb0, va, vc, gp, cc, j0);
  }
  __syncthreads();

  auto tile = [&](int k0, const ushort_t* Kc, const ushort_t* Vc,
                  const float* bc, ushort_t* Kn, ushort_t* Vn, float* bn,
                  bool pf) {
    // ---- issue next tile's loads FIRST (latency hides under compute)
    uint4 va, vc2;
    if (pf) {
      const int k1 = k0 + 64;
#pragma unroll
      for (int u = 0; u < 2; ++u)
        gload_lds16(kbase + (size_t)(k1 + w * 16 + u * 8 + kr) * rs + kgc * 8,
                    &Kn[(w * 16 + u * 8) * 64]);
      const ushort_t* vp = vbase + (size_t)(k1 + 2 * kp) * rs + cc * 8;
      va = *(const uint4*)vp;
      vc2 = *(const uint4*)(vp + rs);
      if (tid < 64) bn[tid] = bptr[k1 + tid];
    }

    // ---- hoisted K fragments (A operand: m=l15=key-in-block, k=quad*8+j=d)
    bf16x8 kf0[4], kf1[4];
#pragma unroll
    for (int nb = 0; nb < 4; ++nb) {
      int key = nb * 16 + l15;
      int p0 = (quad ^ (key & 7)) * 8;
      kf0[nb] = *(const bf16x8*)(&Kc[key * 64 + p0]);
      kf1[nb] = *(const bf16x8*)(&Kc[key * 64 + (p0 ^ 32)]);
    }
    // ---- hoisted V fragments (B operand under pi)
    bf16x8 vf0[4], vf1[4];
#pragma unroll
    for (int nbd = 0; nbd < 4; ++nbd) {
      vf0[nbd] = *(const bf16x8*)(&Vc[quad * 520 + (nbd * 16 + l15) * 8]);
      vf1[nbd] = *(const bf16x8*)(&Vc[(4 + quad) * 520 + (nbd * 16 + l15) * 8]);
    }

#pragma unroll
    for (int qb = 0; qb < 2; ++qb) {
      // S^T = K Q^T: st[nb][i] = S[key=nb*16+quad*4+i][q=l15]
      f32x4 st[4];
#pragma unroll
      for (int nb = 0; nb < 4; ++nb) {
        f32x4 s = (f32x4){0.f, 0.f, 0.f, 0.f};
        s = __builtin_amdgcn_mfma_f32_16x16x32_bf16(kf0[nb], qf[qb][0], s, 0, 0, 0);
        s = __builtin_amdgcn_mfma_f32_16x16x32_bf16(kf1[nb], qf[qb][1], s, 0, 0, 0);
        st[nb] = s;
      }
      // p = exp2(s*SC + bias); bias f32x4 aligns with reg i.
      float pp[4][4];
      float racc = 0.f;
#pragma unroll
      for (int nb = 0; nb < 4; ++nb) {
        f32x4 bv = *(const f32x4*)&bc[nb * 16 + quad * 4];
#pragma unroll
        for (int i = 0; i < 4; ++i) {
          float p = __builtin_amdgcn_exp2f(st[nb][i] * SC_LOG2 + bv[i]);
          pp[nb][i] = p;
          racc += p;
        }
      }
      rsum[qb] += racc;
      // pack P A-frags (in-lane; key order matches pi)
      union { uint4 u; bf16x8 v; } pf0, pf1;
      pf0.u.x = pack2bf(pp[0][0], pp[0][1]);
      pf0.u.y = pack2bf(pp[0][2], pp[0][3]);
      pf0.u.z = pack2bf(pp[1][0], pp[1][1]);
      pf0.u.w = pack2bf(pp[1][2], pp[1][3]);
      pf1.u.x = pack2bf(pp[2][0], pp[2][1]);
      pf1.u.y = pack2bf(pp[2][2], pp[2][3]);
      pf1.u.z = pack2bf(pp[3][0], pp[3][1]);
      pf1.u.w = pack2bf(pp[3][2], pp[3][3]);
      // O += P V (pi-consistent)
#pragma unroll
      for (int nbd = 0; nbd < 4; ++nbd) {
        Oa[qb][nbd] = __builtin_amdgcn_mfma_f32_16x16x32_bf16(
            pf0.v, vf0[nbd], Oa[qb][nbd], 0, 0, 0);
        Oa[qb][nbd] = __builtin_amdgcn_mfma_f32_16x16x32_bf16(
            pf1.v, vf1[nbd], Oa[qb][nbd], 0, 0, 0);
      }
    }

    // ---- finish staging next tile: V regs -> LDS (vmcnt wait is free by now)
    if (pf) v_pack_store(Vn, va, vc2, gp, cc, j0);
    __syncthreads();
  };

  for (int k0 = 0; k0 < T_; k0 += 128) {
    tile(k0,      Kb0, Vb0, bsh0, Kb1, Vb1, bsh1, true);
    tile(k0 + 64, Kb1, Vb1, bsh1, Kb0, Vb0, bsh0, k0 + 128 < T_);
  }

  // ---- epilogue: rsum lives at q=l15; redistribute via per-wave LDS.
#pragma unroll
  for (int qb = 0; qb < 2; ++qb) {
    float r = rsum[qb];
    r += __shfl_xor(r, 16, 64);
    r += __shfl_xor(r, 32, 64);
    if (lane < 16) lsum[w][qb * 16 + lane] = r;
  }
  // Ost aliases Kb/Vb — safe: final tile ended with __syncthreads().
  ushort_t* OstW = (ushort_t*)(smem) + w * (32 * 72);
  // same-wave LDS write->read: ordered by lgkmcnt, no barrier needed.
#pragma unroll
  for (int qb = 0; qb < 2; ++qb) {
    f32x4 lr = *(const f32x4*)&lsum[w][qb * 16 + quad * 4];
    f32x4 invl;
#pragma unroll
    for (int i = 0; i < 4; ++i) invl[i] = 1.0f / lr[i];
#pragma unroll
    for (int nbd = 0; nbd < 4; ++nbd)
#pragma unroll
      for (int i = 0; i < 4; ++i)
        OstW[(qb * 16 + quad * 4 + i) * 72 + nbd * 16 + l15] =
            f2bf_fast(Oa[qb][nbd][i] * invl[i]);
  }
  ushort_t* dst = oat + (size_t)(b * T_ + q0 + w * 32) * D_ + h * HD_;
#pragma unroll
  for (int pp = 0; pp < 4; ++pp) {
    int row = pp * 8 + (lane >> 3), c = lane & 7;
    uint4 v = *(const uint4*)&OstW[row * 72 + c * 8];
    *(uint4*)&dst[(size_t)row * D_ + c * 8] = v;
  }
}

// ---------------------------------------------------------------------------
extern "C" void kernel_launch(void* const* d_in, const int* in_sizes, int n_in,
                              void* d_out, int out_size, void* d_ws, size_t ws_size,
                              hipStream_t stream) {
  const float* x     = (const float*)d_in[0];
  const float* eng   = (const float*)d_in[1];
  const int*   mask  = (const int*)d_in[2];
  const float* qkv_w = (const float*)d_in[3];
  const float* qkv_b = (const float*)d_in[4];
  const float* out_w = (const float*)d_in[5];
  const float* out_b = (const float*)d_in[6];
  float* out = (float*)d_out;

  const int M = B_ * T_;
  const size_t nx = (size_t)M * D_;
  const size_t nwq = (size_t)3 * D_ * D_;
  const size_t nwo = (size_t)D_ * D_;
  const size_t nqkv = (size_t)M * 3 * D_;

  char* p = (char*)d_ws;
  ushort_t* xb    = (ushort_t*)p;            p += nx * 2;
  ushort_t* wqkvb = (ushort_t*)p;            p += nwq * 2;
  ushort_t* woutb = (ushort_t*)p;            p += nwo * 2;
  ushort_t* qkvb  = (ushort_t*)p;            p += nqkv * 2;
  ushort_t* oatb  = (ushort_t*)p;            p += nx * 2;
  float*    biasA = (float*)p;               p += (size_t)M * 4;

  cvt_bf16<<<(int)(nx / 1024), 256, 0, stream>>>(x, xb, (int)nx);
  cvt_bf16<<<(int)(nwq / 1024), 256, 0, stream>>>(qkv_w, wqkvb, (int)nwq);
  cvt_bf16<<<(int)(nwo / 1024), 256, 0, stream>>>(out_w, woutb, (int)nwo);
  bias_prep<<<M / 256, 256, 0, stream>>>(eng, mask, biasA, M);

  gemm_bf16<1><<<dim3(3 * D_ / 128, M / 128), 256, 0, stream>>>(
      xb, wqkvb, qkv_b, qkvb, M, 3 * D_, D_);
  attn_mfma<<<dim3(T_ / 128, H_, B_), 256, 0, stream>>>(qkvb, biasA, oatb);
  gemm_bf16<0><<<dim3(D_ / 128, M / 128), 256, 0, stream>>>(
      oatb, woutb, out_b, out, M, D_, D_);
}

// Round 2
// 309.827 us; speedup vs baseline: 3.2388x; 3.2388x over previous
//
#include <hip/hip_runtime.h>
#include <math.h>

// B=4, T=2048, D=1024, H=16, HD=64
#define B_  4
#define T_  2048
#define D_  1024
#define H_  16
#define HD_ 64

typedef unsigned short ushort_t;
typedef unsigned int uint_t;
typedef __attribute__((ext_vector_type(8))) short bf16x8;
typedef __attribute__((ext_vector_type(4))) float f32x4;

// 0.125 * log2(e): folds 1/sqrt(HD) and exp->exp2.
#define SC_LOG2 0.1803368801111243f

__device__ inline ushort_t f2bf(float f) {           // RNE
  uint_t u = __float_as_uint(f);
  u += 0x7fffu + ((u >> 16) & 1u);
  return (ushort_t)(u >> 16);
}
__device__ inline ushort_t f2bf_fast(float f) {      // round-half-away
  return (ushort_t)((__float_as_uint(f) + 0x8000u) >> 16);
}
__device__ inline uint_t pack2bf(float a, float b) { // (a lo16, b hi16)
  uint_t ua = (__float_as_uint(a) + 0x8000u) >> 16;
  uint_t ub = (__float_as_uint(b) + 0x8000u) & 0xffff0000u;
  return ua | ub;
}

__device__ inline void gload_lds16(const ushort_t* g, ushort_t* l) {
  __builtin_amdgcn_global_load_lds(
      (const __attribute__((address_space(1))) unsigned int*)g,
      (__attribute__((address_space(3))) unsigned int*)l, 16, 0, 0);
}

// ---------------------------------------------------------------------------
__global__ __launch_bounds__(256) void cvt_bf16(const float* __restrict__ in,
                                                ushort_t* __restrict__ out, int n) {
  int i = (blockIdx.x * 256 + threadIdx.x) * 4;
  if (i + 3 < n) {
    float4 v = *(const float4*)(in + i);
    uint_t lo = (uint_t)f2bf(v.x) | ((uint_t)f2bf(v.y) << 16);
    uint_t hi = (uint_t)f2bf(v.z) | ((uint_t)f2bf(v.w) << 16);
    *(uint2*)(out + i) = make_uint2(lo, hi);
  }
}

// per-key bias in log2 domain: masked ? -1e30 : log2(clip(engagement,1e-6))
__global__ __launch_bounds__(256) void bias_prep(const float* __restrict__ eng,
                                                 const int* __restrict__ mask,
                                                 float* __restrict__ biasA, int n) {
  int i = blockIdx.x * 256 + threadIdx.x;
  if (i < n) biasA[i] = mask[i] ? -1e30f : __log2f(fmaxf(eng[i], 1e-6f));
}

// ---------------------------------------------------------------------------
// C[M,N] = A[M,K] @ B[N,K]^T + bias[N]. (unchanged)
// ---------------------------------------------------------------------------
template <int WRITE_BF16>
__global__ __launch_bounds__(256) void gemm_bf16(
    const ushort_t* __restrict__ A, const ushort_t* __restrict__ Bm,
    const float* __restrict__ bias, void* __restrict__ Cout,
    int M, int N, int K) {
  __shared__ __align__(16) ushort_t Ls[8192];
  ushort_t* As = Ls;
  ushort_t* Bs = Ls + 4096;
  const int tid = threadIdx.x;
  const int w = tid >> 6, lane = tid & 63;
  const int l15 = lane & 15, quad = lane >> 4;
  const int wm = w >> 1, wn = w & 1;
  const int m0 = blockIdx.y * 128, n0 = blockIdx.x * 128;

  f32x4 acc[4][4];
#pragma unroll
  for (int a = 0; a < 4; ++a)
#pragma unroll
    for (int b = 0; b < 4; ++b) acc[a][b] = (f32x4){0.f, 0.f, 0.f, 0.f};

  const int sr = lane >> 2;
  const int gc = (lane & 3) ^ ((sr >> 1) & 3);

  for (int k0 = 0; k0 < K; k0 += 32) {
    __syncthreads();
#pragma unroll
    for (int u = 0; u < 2; ++u) {
      int row = w * 32 + u * 16 + sr;
      gload_lds16(A + (size_t)(m0 + row) * K + k0 + gc * 8,
                  &As[(w * 32 + u * 16) * 32]);
      gload_lds16(Bm + (size_t)(n0 + row) * K + k0 + gc * 8,
                  &Bs[(w * 32 + u * 16) * 32]);
    }
    __syncthreads();
    bf16x8 af[4], bf[4];
#pragma unroll
    for (int mb = 0; mb < 4; ++mb) {
      int row = wm * 64 + mb * 16 + l15;
      int p = quad ^ ((l15 >> 1) & 3);
      af[mb] = *(const bf16x8*)(&As[row * 32 + p * 8]);
    }
#pragma unroll
    for (int nb = 0; nb < 4; ++nb) {
      int row = wn * 64 + nb * 16 + l15;
      int p = quad ^ ((l15 >> 1) & 3);
      bf[nb] = *(const bf16x8*)(&Bs[row * 32 + p * 8]);
    }
#pragma unroll
    for (int mb = 0; mb < 4; ++mb)
#pragma unroll
      for (int nb = 0; nb < 4; ++nb)
        acc[mb][nb] = __builtin_amdgcn_mfma_f32_16x16x32_bf16(
            af[mb], bf[nb], acc[mb][nb], 0, 0, 0);
  }

  float bb[4];
#pragma unroll
  for (int nb = 0; nb < 4; ++nb) bb[nb] = bias[n0 + wn * 64 + nb * 16 + l15];

  if (WRITE_BF16) {
    ushort_t* Cb = (ushort_t*)Cout;
#pragma unroll
    for (int mb = 0; mb < 4; ++mb) {
      __syncthreads();
#pragma unroll
      for (int nb = 0; nb < 4; ++nb)
#pragma unroll
        for (int i = 0; i < 4; ++i) {
          float v = acc[mb][nb][i] + bb[nb];
          Ls[(wm * 16 + quad * 4 + i) * 136 + wn * 64 + nb * 16 + l15] =
              f2bf_fast(v);
        }
      __syncthreads();
      int lr = tid >> 3, c = tid & 7;
      size_t gr = (size_t)(m0 + (lr >> 4) * 64 + mb * 16 + (lr & 15));
      uint4 v0 = *(const uint4*)&Ls[lr * 136 + c * 16];
      uint4 v1 = *(const uint4*)&Ls[lr * 136 + c * 16 + 8];
      *(uint4*)&Cb[gr * N + n0 + c * 16] = v0;
      *(uint4*)&Cb[gr * N + n0 + c * 16 + 8] = v1;
    }
  } else {
    float* Cf = (float*)Cout;
#pragma unroll
    for (int mb = 0; mb < 4; ++mb)
#pragma unroll
      for (int i = 0; i < 4; ++i) {
        size_t row = (size_t)(m0 + wm * 64 + mb * 16 + quad * 4 + i);
#pragma unroll
        for (int nb = 0; nb < 4; ++nb)
          Cf[row * N + n0 + wn * 64 + nb * 16 + l15] = acc[mb][nb][i] + bb[nb];
      }
  }
}

// ---------------------------------------------------------------------------
// MFMA flash attention, S^T formulation, software-pipelined:
// double-buffered K/V/bias, ONE barrier per 64-key tile, next tile's global
// loads issued before current tile's compute. Tile body is a MACRO (textual
// inline) — R1's lambda was outlined by the compiler, which demoted all
// by-reference captures (Oa, qf, rsum) to scratch: VGPR 96->64 and ~3.6 GB/
// dispatch of scratch HBM traffic. Never hide pipelined state behind a call.
// LDS (34048 B, 4 blocks/CU):
//   Kb0 @0 (8192) | Kb1 @8192 (8192) | Vb0 @16384 (8320) | Vb1 @24704 (8320)
//   bsh0 @33024 (256) | bsh1 @33280 (256) | lsum @33536 (512)
//   Ost @0 (18432) — epilogue only, aliases Kb/Vb (safe after final barrier)
// ---------------------------------------------------------------------------

// One 64-key tile: prefetch next (K via global_load_lds, V via regs, bias),
// compute current, then write staged V regs to LDS and barrier.
#define ATTN_TILE(K0, Kc, Vc, bc, Kn, Vn, bn, PF)                              \
  {                                                                            \
    uint4 va_, vc_;                                                            \
    const bool pf_ = (PF);                                                     \
    if (pf_) {                                                                 \
      const int k1_ = (K0) + 64;                                               \
      _Pragma("unroll")                                                        \
      for (int u = 0; u < 2; ++u)                                              \
        gload_lds16(kbase + (size_t)(k1_ + w * 16 + u * 8 + kr) * rs + kgc * 8,\
                    &(Kn)[(w * 16 + u * 8) * 64]);                             \
      const ushort_t* vp_ = vbase + (size_t)(k1_ + 2 * kp) * rs + cc * 8;      \
      va_ = *(const uint4*)vp_;                                                \
      vc_ = *(const uint4*)(vp_ + rs);                                         \
      if (tid < 64) (bn)[tid] = bptr[k1_ + tid];                               \
    }                                                                          \
    bf16x8 kf0[4], kf1[4];                                                     \
    _Pragma("unroll")                                                          \
    for (int nb = 0; nb < 4; ++nb) {                                           \
      int key = nb * 16 + l15;                                                 \
      int p0 = (quad ^ (key & 7)) * 8;                                         \
      kf0[nb] = *(const bf16x8*)(&(Kc)[key * 64 + p0]);                        \
      kf1[nb] = *(const bf16x8*)(&(Kc)[key * 64 + (p0 ^ 32)]);                 \
    }                                                                          \
    bf16x8 vf0[4], vf1[4];                                                     \
    _Pragma("unroll")                                                          \
    for (int nbd = 0; nbd < 4; ++nbd) {                                        \
      vf0[nbd] = *(const bf16x8*)(&(Vc)[quad * 520 + (nbd * 16 + l15) * 8]);   \
      vf1[nbd] =                                                               \
          *(const bf16x8*)(&(Vc)[(4 + quad) * 520 + (nbd * 16 + l15) * 8]);    \
    }                                                                          \
    _Pragma("unroll")                                                          \
    for (int qb = 0; qb < 2; ++qb) {                                           \
      f32x4 st[4];                                                             \
      _Pragma("unroll")                                                        \
      for (int nb = 0; nb < 4; ++nb) {                                         \
        f32x4 s = (f32x4){0.f, 0.f, 0.f, 0.f};                                 \
        s = __builtin_amdgcn_mfma_f32_16x16x32_bf16(kf0[nb], qf[qb][0], s, 0,  \
                                                    0, 0);                     \
        s = __builtin_amdgcn_mfma_f32_16x16x32_bf16(kf1[nb], qf[qb][1], s, 0,  \
                                                    0, 0);                     \
        st[nb] = s;                                                            \
      }                                                                        \
      float pp[4][4];                                                          \
      float racc = 0.f;                                                        \
      _Pragma("unroll")                                                        \
      for (int nb = 0; nb < 4; ++nb) {                                         \
        f32x4 bv = *(const f32x4*)&(bc)[nb * 16 + quad * 4];                   \
        _Pragma("unroll")                                                      \
        for (int i = 0; i < 4; ++i) {                                          \
          float p = __builtin_amdgcn_exp2f(st[nb][i] * SC_LOG2 + bv[i]);       \
          pp[nb][i] = p;                                                       \
          racc += p;                                                           \
        }                                                                      \
      }                                                                        \
      rsum[qb] += racc;                                                        \
      union { uint4 u; bf16x8 v; } pf0, pf1;                                   \
      pf0.u.x = pack2bf(pp[0][0], pp[0][1]);                                   \
      pf0.u.y = pack2bf(pp[0][2], pp[0][3]);                                   \
      pf0.u.z = pack2bf(pp[1][0], pp[1][1]);                                   \
      pf0.u.w = pack2bf(pp[1][2], pp[1][3]);                                   \
      pf1.u.x = pack2bf(pp[2][0], pp[2][1]);                                   \
      pf1.u.y = pack2bf(pp[2][2], pp[2][3]);                                   \
      pf1.u.z = pack2bf(pp[3][0], pp[3][1]);                                   \
      pf1.u.w = pack2bf(pp[3][2], pp[3][3]);                                   \
      _Pragma("unroll")                                                        \
      for (int nbd = 0; nbd < 4; ++nbd) {                                      \
        Oa[qb][nbd] = __builtin_amdgcn_mfma_f32_16x16x32_bf16(                 \
            pf0.v, vf0[nbd], Oa[qb][nbd], 0, 0, 0);                            \
        Oa[qb][nbd] = __builtin_amdgcn_mfma_f32_16x16x32_bf16(                 \
            pf1.v, vf1[nbd], Oa[qb][nbd], 0, 0, 0);                            \
      }                                                                        \
    }                                                                          \
    if (pf_) {                                                                 \
      uint_t* dst_ = (uint_t*)&(Vn)[gp * 520 + cc * 64 + j0];                  \
      dst_[0]  = (va_.x & 0xffffu) | (vc_.x << 16);                            \
      dst_[4]  = (va_.x >> 16)     | (vc_.x & 0xffff0000u);                    \
      dst_[8]  = (va_.y & 0xffffu) | (vc_.y << 16);                            \
      dst_[12] = (va_.y >> 16)     | (vc_.y & 0xffff0000u);                    \
      dst_[16] = (va_.z & 0xffffu) | (vc_.z << 16);                            \
      dst_[20] = (va_.z >> 16)     | (vc_.z & 0xffff0000u);                    \
      dst_[24] = (va_.w & 0xffffu) | (vc_.w << 16);                            \
      dst_[28] = (va_.w >> 16)     | (vc_.w & 0xffff0000u);                    \
    }                                                                          \
    __syncthreads();                                                           \
  }

__global__ __launch_bounds__(256) void attn_mfma(
    const ushort_t* __restrict__ qkv, const float* __restrict__ biasA,
    ushort_t* __restrict__ oat) {
  __shared__ __align__(16) char smem[34048];
  ushort_t* Kb0 = (ushort_t*)(smem);
  ushort_t* Kb1 = (ushort_t*)(smem + 8192);
  ushort_t* Vb0 = (ushort_t*)(smem + 16384);
  ushort_t* Vb1 = (ushort_t*)(smem + 24704);
  float* bsh0 = (float*)(smem + 33024);
  float* bsh1 = (float*)(smem + 33280);
  float (*lsum)[32] = (float (*)[32])(smem + 33536);

  const int b = blockIdx.z, h = blockIdx.y;
  const int q0 = blockIdx.x * 128;
  const int tid = threadIdx.x;
  const int w = tid >> 6, lane = tid & 63;
  const int l15 = lane & 15, quad = lane >> 4;
  const size_t rs = 3 * D_;

  // Q B-frags (n=l15=q, k=quad*8+j=d) for the wave's 2 q-blocks.
  bf16x8 qf[2][2];
#pragma unroll
  for (int qb = 0; qb < 2; ++qb) {
    const ushort_t* qp =
        qkv + (size_t)(b * T_ + q0 + w * 32 + qb * 16 + l15) * rs + h * HD_;
    qf[qb][0] = *(const bf16x8*)(qp + quad * 8);
    qf[qb][1] = *(const bf16x8*)(qp + 32 + quad * 8);
  }

  f32x4 Oa[2][4];
#pragma unroll
  for (int qb = 0; qb < 2; ++qb)
#pragma unroll
    for (int nb = 0; nb < 4; ++nb) Oa[qb][nb] = (f32x4){0.f, 0.f, 0.f, 0.f};
  float rsum[2] = {0.f, 0.f};

  const ushort_t* kbase = qkv + (size_t)(b * T_) * rs + D_ + h * HD_;
  const ushort_t* vbase = kbase + D_;
  const float* bptr = biasA + b * T_;

  const int kr = lane >> 3, kc = lane & 7;
  const int kgc = kc ^ kr;
  const int kp = tid & 31, cc = tid >> 5;
  const int gp = (kp >> 4) * 4 + ((kp >> 1) & 3);
  const int j0 = ((kp >> 3) & 1) * 4 + 2 * (kp & 1);

  // ---- prologue: stage tile 0 into buf0
  {
#pragma unroll
    for (int u = 0; u < 2; ++u)
      gload_lds16(kbase + (size_t)(w * 16 + u * 8 + kr) * rs + kgc * 8,
                  &Kb0[(w * 16 + u * 8) * 64]);
    const ushort_t* vp = vbase + (size_t)(2 * kp) * rs + cc * 8;
    uint4 va = *(const uint4*)vp;
    uint4 vc = *(const uint4*)(vp + rs);
    if (tid < 64) bsh0[tid] = bptr[tid];
    uint_t* dst = (uint_t*)&Vb0[gp * 520 + cc * 64 + j0];
    dst[0]  = (va.x & 0xffffu) | (vc.x << 16);
    dst[4]  = (va.x >> 16)     | (vc.x & 0xffff0000u);
    dst[8]  = (va.y & 0xffffu) | (vc.y << 16);
    dst[12] = (va.y >> 16)     | (vc.y & 0xffff0000u);
    dst[16] = (va.z & 0xffffu) | (vc.z << 16);
    dst[20] = (va.z >> 16)     | (vc.z & 0xffff0000u);
    dst[24] = (va.w & 0xffffu) | (vc.w << 16);
    dst[28] = (va.w >> 16)     | (vc.w & 0xffff0000u);
  }
  __syncthreads();

  for (int k0 = 0; k0 < T_; k0 += 128) {
    ATTN_TILE(k0,      Kb0, Vb0, bsh0, Kb1, Vb1, bsh1, true);
    ATTN_TILE(k0 + 64, Kb1, Vb1, bsh1, Kb0, Vb0, bsh0, k0 + 128 < T_);
  }

  // ---- epilogue: rsum lives at q=l15; redistribute via per-wave LDS.
#pragma unroll
  for (int qb = 0; qb < 2; ++qb) {
    float r = rsum[qb];
    r += __shfl_xor(r, 16, 64);
    r += __shfl_xor(r, 32, 64);
    if (lane < 16) lsum[w][qb * 16 + lane] = r;
  }
  // Ost aliases Kb/Vb — safe: final tile ended with __syncthreads().
  ushort_t* OstW = (ushort_t*)(smem) + w * (32 * 72);
  // same-wave LDS write->read: ordered by lgkmcnt, no barrier needed.
#pragma unroll
  for (int qb = 0; qb < 2; ++qb) {
    f32x4 lr = *(const f32x4*)&lsum[w][qb * 16 + quad * 4];
    f32x4 invl;
#pragma unroll
    for (int i = 0; i < 4; ++i) invl[i] = 1.0f / lr[i];
#pragma unroll
    for (int nbd = 0; nbd < 4; ++nbd)
#pragma unroll
      for (int i = 0; i < 4; ++i)
        OstW[(qb * 16 + quad * 4 + i) * 72 + nbd * 16 + l15] =
            f2bf_fast(Oa[qb][nbd][i] * invl[i]);
  }
  ushort_t* dst = oat + (size_t)(b * T_ + q0 + w * 32) * D_ + h * HD_;
#pragma unroll
  for (int pp = 0; pp < 4; ++pp) {
    int row = pp * 8 + (lane >> 3), c = lane & 7;
    uint4 v = *(const uint4*)&OstW[row * 72 + c * 8];
    *(uint4*)&dst[(size_t)row * D_ + c * 8] = v;
  }
}

// ---------------------------------------------------------------------------
extern "C" void kernel_launch(void* const* d_in, const int* in_sizes, int n_in,
                              void* d_out, int out_size, void* d_ws, size_t ws_size,
                              hipStream_t stream) {
  const float* x     = (const float*)d_in[0];
  const float* eng   = (const float*)d_in[1];
  const int*   mask  = (const int*)d_in[2];
  const float* qkv_w = (const float*)d_in[3];
  const float* qkv_b = (const float*)d_in[4];
  const float* out_w = (const float*)d_in[5];
  const float* out_b = (const float*)d_in[6];
  float* out = (float*)d_out;

  const int M = B_ * T_;
  const size_t nx = (size_t)M * D_;
  const size_t nwq = (size_t)3 * D_ * D_;
  const size_t nwo = (size_t)D_ * D_;
  const size_t nqkv = (size_t)M * 3 * D_;

  char* p = (char*)d_ws;
  ushort_t* xb    = (ushort_t*)p;            p += nx * 2;
  ushort_t* wqkvb = (ushort_t*)p;            p += nwq * 2;
  ushort_t* woutb = (ushort_t*)p;            p += nwo * 2;
  ushort_t* qkvb  = (ushort_t*)p;            p += nqkv * 2;
  ushort_t* oatb  = (ushort_t*)p;            p += nx * 2;
  float*    biasA = (float*)p;               p += (size_t)M * 4;

  cvt_bf16<<<(int)(nx / 1024), 256, 0, stream>>>(x, xb, (int)nx);
  cvt_bf16<<<(int)(nwq / 1024), 256, 0, stream>>>(qkv_w, wqkvb, (int)nwq);
  cvt_bf16<<<(int)(nwo / 1024), 256, 0, stream>>>(out_w, woutb, (int)nwo);
  bias_prep<<<M / 256, 256, 0, stream>>>(eng, mask, biasA, M);

  gemm_bf16<1><<<dim3(3 * D_ / 128, M / 128), 256, 0, stream>>>(
      xb, wqkvb, qkv_b, qkvb, M, 3 * D_, D_);
  attn_mfma<<<dim3(T_ / 128, H_, B_), 256, 0, stream>>>(qkvb, biasA, oatb);
  gemm_bf16<0><<<dim3(D_ / 128, M / 128), 256, 0, stream>>>(
      oatb, woutb, out_b, out, M, D_, D_);
}